// Round 1
// baseline (17067.416 us; speedup 1.0000x reference)
//
#include <hip/hip_runtime.h>
#include <hip/hip_bf16.h>

#define N_   64
#define T_   1024
#define IN_  64
#define H1_  512
#define H2_  256
#define K1_  576    // IN_ + H1_
#define K2_  768    // H1_ + H2_
#define NBLK 48

typedef __bf16 bf16x8 __attribute__((ext_vector_type(8)));
typedef float  f32x4  __attribute__((ext_vector_type(4)));
typedef unsigned int u32x4 __attribute__((ext_vector_type(4)));
typedef __hip_bfloat16 bf16_t;

// ---------------- workspace layout (bytes) ----------------
#define OFF_C1    0u            // 131072 (unused scratch, kept for layout)
#define OFF_C2    131072u       // 65536
#define OFF_H1B   196608u       // 2 * 64*512*2 = 131072
#define OFF_H2B   327680u       // 2 * 64*256*2 = 65536
#define OFF_BAR   393216u       // 256
#define ZERO_BYTES 393472u
#define OFF_XB    393472u       // 64*1024*64*2 = 8388608
#define OFF_W1    8782080u      // 2048*576*2 = 2359296
#define OFF_W2    11141376u     // 1024*768*2 = 1572864
#define OFF_B1    12714240u     // 2048*4
#define OFF_B2    12722432u     // 1024*4
#define OFF_FC1W  12726528u     // 128*512*2 = 131072
#define OFF_FC2W  12857600u     // 64*128*2 = 16384
#define OFF_HS2   12873984u     // 64*1024*256*2 = 33554432
#define OFF_HST   46428416u     // 33554432  -> end 79982848 (~80 MB)

__device__ __forceinline__ bf16x8 ld16(const bf16_t* p) {
  u32x4 u = *reinterpret_cast<const u32x4*>(p);
  return __builtin_bit_cast(bf16x8, u);
}
__device__ __forceinline__ f32x4 mfma_bf16(bf16x8 a, bf16x8 b, f32x4 c) {
  return __builtin_amdgcn_mfma_f32_16x16x32_bf16(a, b, c, 0, 0, 0);
}
__device__ __forceinline__ float sigf(float x) { return 1.f / (1.f + __expf(-x)); }
__device__ __forceinline__ float tanh_fast(float x) {
  float e = __expf(-2.f * fabsf(x));
  float r = (1.f - e) / (1.f + e);
  return x < 0.f ? -r : r;
}

// ---------------- setup: bf16 conversion / packing ----------------
__global__ void setup_kernel(const float* __restrict__ x,
    const float* __restrict__ Wih1, const float* __restrict__ Whh1,
    const float* __restrict__ bih1, const float* __restrict__ bhh1,
    const float* __restrict__ Wih2, const float* __restrict__ Whh2,
    const float* __restrict__ bih2, const float* __restrict__ bhh2,
    const float* __restrict__ fc1w, const float* __restrict__ fc2w,
    char* __restrict__ ws)
{
  bf16_t* xb = (bf16_t*)(ws + OFF_XB);
  bf16_t* w1 = (bf16_t*)(ws + OFF_W1);
  bf16_t* w2 = (bf16_t*)(ws + OFF_W2);
  float*  b1 = (float*)(ws + OFF_B1);
  float*  b2 = (float*)(ws + OFF_B2);
  bf16_t* f1 = (bf16_t*)(ws + OFF_FC1W);
  bf16_t* f2 = (bf16_t*)(ws + OFF_FC2W);
  const long E0 = 4194304, E1 = E0 + 1179648, E2 = E1 + 786432,
             E3 = E2 + 2048, E4 = E3 + 1024, E5 = E4 + 65536, E6 = E5 + 8192;
  for (long i = blockIdx.x * (long)blockDim.x + threadIdx.x; i < E6;
       i += (long)gridDim.x * blockDim.x) {
    if (i < E0) {
      xb[i] = __float2bfloat16(x[i]);
    } else if (i < E1) {                       // W1[j][k] = concat(Wih1, Whh1) rows
      long idx = i - E0; long j = idx / 576, k = idx % 576;
      float v = (k < 64) ? Wih1[j * 64 + k] : Whh1[j * 512 + (k - 64)];
      w1[idx] = __float2bfloat16(v);
    } else if (i < E2) {                       // W2[j][k] = concat(Wih2, Whh2)
      long idx = i - E1; long j = idx / 768, k = idx % 768;
      float v = (k < 512) ? Wih2[j * 512 + k] : Whh2[j * 256 + (k - 512)];
      w2[idx] = __float2bfloat16(v);
    } else if (i < E3) {
      long idx = i - E2; b1[idx] = bih1[idx] + bhh1[idx];
    } else if (i < E4) {
      long idx = i - E3; b2[idx] = bih2[idx] + bhh2[idx];
    } else if (i < E5) {
      long idx = i - E4; f1[idx] = __float2bfloat16(fc1w[idx]);
    } else {                                   // fc2 padded to 64 rows
      long idx = i - E5; long j = idx / 128, k = idx % 128;
      f2[idx] = __float2bfloat16(j < 51 ? fc2w[j * 128 + k] : 0.f);
    }
  }
}

// ---------------- grid barrier (device-scope, sense-reversing) ----------------
__device__ __forceinline__ void grid_barrier(unsigned* cnt, unsigned* sense, unsigned gen) {
  __syncthreads();
  if (threadIdx.x == 0) {
    __threadfence();
    unsigned old = __hip_atomic_fetch_add(cnt, 1u, __ATOMIC_ACQ_REL, __HIP_MEMORY_SCOPE_AGENT);
    if (old == (unsigned)(NBLK - 1)) {
      __hip_atomic_store(cnt, 0u, __ATOMIC_RELAXED, __HIP_MEMORY_SCOPE_AGENT);
      __hip_atomic_store(sense, gen, __ATOMIC_RELEASE, __HIP_MEMORY_SCOPE_AGENT);
    } else {
      unsigned s;
      do {
        __builtin_amdgcn_s_sleep(1);
        s = __hip_atomic_load(sense, __ATOMIC_ACQUIRE, __HIP_MEMORY_SCOPE_AGENT);
      } while (s < gen);
    }
  }
  __syncthreads();
}

// ---------------- persistent LSTM kernel (both layers, pipelined) ----------------
__global__ __launch_bounds__(256, 1) void lstm_kernel(char* __restrict__ ws,
                                                      float* __restrict__ dout)
{
  const bf16_t* xb  = (const bf16_t*)(ws + OFF_XB);
  const bf16_t* W1  = (const bf16_t*)(ws + OFF_W1);
  const bf16_t* W2  = (const bf16_t*)(ws + OFF_W2);
  const float*  b1  = (const float*)(ws + OFF_B1);
  const float*  b2  = (const float*)(ws + OFF_B2);
  bf16_t* h1b = (bf16_t*)(ws + OFF_H1B);
  bf16_t* h2b = (bf16_t*)(ws + OFF_H2B);
  bf16_t* hs2 = (bf16_t*)(ws + OFF_HS2);
  bf16_t* hsT = (bf16_t*)(ws + OFF_HST);
  unsigned* bcnt   = (unsigned*)(ws + OFF_BAR);
  unsigned* bsense = bcnt + 32;

  __shared__ float gbuf[4][64][16];

  const int tid  = threadIdx.x;
  const int wave = tid >> 6;
  const int lane = tid & 63;
  const int l15  = lane & 15;
  const int quad = lane >> 4;
  const int wg   = blockIdx.x;
  const f32x4 z = {0.f, 0.f, 0.f, 0.f};

  if (wg < 32) {
    // ---- LSTM layer 1: wg owns units [wg*16, wg*16+16), wave = gate (i,f,g,o)
    const bf16_t* wrow = W1 + (size_t)(wave * H1_ + wg * 16 + l15) * K1_ + quad * 8;
    bf16x8 wf[18];
    #pragma unroll
    for (int i = 0; i < 18; ++i) {
      int k = (i < 2) ? i * 32 : 64 + (i - 2) * 32;
      wf[i] = ld16(wrow + k);
    }
    int ub[4]; int uu[4];
    float bi[4], bff[4], bg[4], bo[4], creg[4];
    #pragma unroll
    for (int r = 0; r < 4; ++r) {
      int idx = tid + r * 256;
      ub[r] = idx >> 4;
      int u = idx & 15;
      uu[r] = wg * 16 + u;
      bi[r]  = b1[uu[r]];
      bff[r] = b1[H1_ + uu[r]];
      bg[r]  = b1[2 * H1_ + uu[r]];
      bo[r]  = b1[3 * H1_ + uu[r]];
      creg[r] = 0.f;
    }
    #pragma unroll 1
    for (int tau = 0; tau <= T_; ++tau) {
      const int t = tau;
      if (t < T_) {
        const bf16_t* hprev = h1b + ((t & 1) ^ 1) * (N_ * H1_);
        bf16_t* hcur = h1b + (t & 1) * (N_ * H1_);
        f32x4 acc[4] = {z, z, z, z};
        #pragma unroll
        for (int ki = 0; ki < 2; ++ki) {
          #pragma unroll
          for (int mt = 0; mt < 4; ++mt) {
            bf16x8 aw = ld16(xb + ((size_t)(mt * 16 + l15) * T_ + t) * IN_ + ki * 32 + quad * 8);
            acc[mt] = mfma_bf16(aw, wf[ki], acc[mt]);
          }
        }
        #pragma unroll
        for (int ki = 0; ki < 16; ++ki) {
          #pragma unroll
          for (int mt = 0; mt < 4; ++mt) {
            bf16x8 aw = ld16(hprev + (size_t)(mt * 16 + l15) * H1_ + ki * 32 + quad * 8);
            acc[mt] = mfma_bf16(aw, wf[2 + ki], acc[mt]);
          }
        }
        #pragma unroll
        for (int mt = 0; mt < 4; ++mt)
          #pragma unroll
          for (int r = 0; r < 4; ++r)
            gbuf[wave][mt * 16 + quad * 4 + r][l15] = acc[mt][r];
        __syncthreads();
        #pragma unroll
        for (int r = 0; r < 4; ++r) {
          int b = ub[r], ug = uu[r], u = ug - wg * 16;
          float giv = gbuf[0][b][u] + bi[r];
          float gfv = gbuf[1][b][u] + bff[r];
          float ggv = gbuf[2][b][u] + bg[r];
          float gov = gbuf[3][b][u] + bo[r];
          float iv = sigf(giv), fv = sigf(gfv), gv = tanh_fast(ggv), ov = sigf(gov);
          float c = fv * creg[r] + iv * gv;
          creg[r] = c;
          float h = ov * tanh_fast(c);
          hcur[(size_t)b * H1_ + ug] = __float2bfloat16(h);
          if (t == T_ - 1) {
            dout[65536 + b * H1_ + ug] = h;
            dout[98304 + b * H1_ + ug] = c;
          }
        }
      }
      grid_barrier(bcnt, bsense, (unsigned)(tau + 1));
    }
  } else {
    // ---- LSTM layer 2 (one step behind): wg2 owns units [wg2*16, wg2*16+16)
    const int wg2 = wg - 32;
    const bf16_t* wrow = W2 + (size_t)(wave * H2_ + wg2 * 16 + l15) * K2_ + quad * 8;
    bf16x8 wf[24];
    #pragma unroll
    for (int i = 0; i < 24; ++i) {
      int k = (i < 16) ? i * 32 : 512 + (i - 16) * 32;
      wf[i] = ld16(wrow + k);
    }
    int ub[4]; int uu[4];
    float bi[4], bff[4], bg[4], bo[4], creg[4];
    #pragma unroll
    for (int r = 0; r < 4; ++r) {
      int idx = tid + r * 256;
      ub[r] = idx >> 4;
      int u = idx & 15;
      uu[r] = wg2 * 16 + u;
      bi[r]  = b2[uu[r]];
      bff[r] = b2[H2_ + uu[r]];
      bg[r]  = b2[2 * H2_ + uu[r]];
      bo[r]  = b2[3 * H2_ + uu[r]];
      creg[r] = 0.f;
    }
    #pragma unroll 1
    for (int tau = 0; tau <= T_; ++tau) {
      const int t = tau - 1;
      if (t >= 0) {
        const bf16_t* xin   = h1b + (t & 1) * (N_ * H1_);        // h1_t
        const bf16_t* hprev = h2b + ((t & 1) ^ 1) * (N_ * H2_);
        bf16_t* hcur = h2b + (t & 1) * (N_ * H2_);
        f32x4 acc[4] = {z, z, z, z};
        #pragma unroll
        for (int ki = 0; ki < 16; ++ki) {
          #pragma unroll
          for (int mt = 0; mt < 4; ++mt) {
            bf16x8 aw = ld16(xin + (size_t)(mt * 16 + l15) * H1_ + ki * 32 + quad * 8);
            acc[mt] = mfma_bf16(aw, wf[ki], acc[mt]);
          }
        }
        #pragma unroll
        for (int ki = 0; ki < 8; ++ki) {
          #pragma unroll
          for (int mt = 0; mt < 4; ++mt) {
            bf16x8 aw = ld16(hprev + (size_t)(mt * 16 + l15) * H2_ + ki * 32 + quad * 8);
            acc[mt] = mfma_bf16(aw, wf[16 + ki], acc[mt]);
          }
        }
        #pragma unroll
        for (int mt = 0; mt < 4; ++mt)
          #pragma unroll
          for (int r = 0; r < 4; ++r)
            gbuf[wave][mt * 16 + quad * 4 + r][l15] = acc[mt][r];
        __syncthreads();
        #pragma unroll
        for (int r = 0; r < 4; ++r) {
          int b = ub[r], ug = uu[r], u = ug - wg2 * 16;
          float giv = gbuf[0][b][u] + bi[r];
          float gfv = gbuf[1][b][u] + bff[r];
          float ggv = gbuf[2][b][u] + bg[r];
          float gov = gbuf[3][b][u] + bo[r];
          float iv = sigf(giv), fv = sigf(gfv), gv = tanh_fast(ggv), ov = sigf(gov);
          float c = fv * creg[r] + iv * gv;
          creg[r] = c;
          float h = ov * tanh_fast(c);
          hcur[(size_t)b * H2_ + ug] = __float2bfloat16(h);
          hs2[((size_t)b * T_ + t) * H2_ + ug] = __float2bfloat16(h);
          hsT[((size_t)b * H2_ + ug) * T_ + t] = __float2bfloat16(h);
          if (t == T_ - 1) {
            dout[131072 + b * H2_ + ug] = h;
            dout[147456 + b * H2_ + ug] = c;
          }
        }
      }
      grid_barrier(bcnt, bsense, (unsigned)(tau + 1));
    }
  }
}

// ---------------- flash attention + fused FC head ----------------
__global__ __launch_bounds__(256, 2) void attn_fc_kernel(
    const char* __restrict__ ws,
    const float* __restrict__ fc1b, const float* __restrict__ fc2b,
    const float* __restrict__ fc3w, const float* __restrict__ fc3b,
    float* __restrict__ dout)
{
  const bf16_t* hs2 = (const bf16_t*)(ws + OFF_HS2);
  const bf16_t* hsT = (const bf16_t*)(ws + OFF_HST);
  const bf16_t* f1w = (const bf16_t*)(ws + OFF_FC1W);
  const bf16_t* f2w = (const bf16_t*)(ws + OFF_FC2W);

  __shared__ __align__(16) unsigned char smem[51200];
  bf16_t* ctxlds = (bf16_t*)smem;             // [64][264]  (33792 B)
  bf16_t* act1   = (bf16_t*)(smem + 33792);   // [64][136]  (17408 B), after s-loop
  bf16_t* plds   = (bf16_t*)(smem + 33792);   // wave w: +w*1152 elems, [16][72] (s-loop only)
  float*  act2   = (float*)smem;              // [64][68]   (17408 B), after fc1

  const int tid  = threadIdx.x;
  const int wave = tid >> 6, lane = tid & 63;
  const int l15  = lane & 15, quad = lane >> 4;
  const int n  = blockIdx.x >> 4;
  const int qt = blockIdx.x & 15;
  const int q0 = qt * 64;
  const f32x4 z = {0.f, 0.f, 0.f, 0.f};

  // Q fragments for this wave's 16 query rows
  bf16x8 aq[8];
  #pragma unroll
  for (int ks = 0; ks < 8; ++ks)
    aq[ks] = ld16(hs2 + ((size_t)n * T_ + q0 + wave * 16 + l15) * H2_ + ks * 32 + quad * 8);

  f32x4 o[16];
  #pragma unroll
  for (int ct = 0; ct < 16; ++ct) o[ct] = z;
  float m_run[4], l_run[4];
  #pragma unroll
  for (int r = 0; r < 4; ++r) { m_run[r] = -1e30f; l_run[r] = 0.f; }

  bf16_t* pw = plds + wave * 1152;

  #pragma unroll 1
  for (int st = 0; st <= qt; ++st) {
    const int s0 = st * 64;
    f32x4 sc[4] = {z, z, z, z};
    #pragma unroll
    for (int ks = 0; ks < 8; ++ks) {
      #pragma unroll
      for (int nt = 0; nt < 4; ++nt) {
        bf16x8 bk = ld16(hs2 + ((size_t)n * T_ + s0 + nt * 16 + l15) * H2_ + ks * 32 + quad * 8);
        sc[nt] = mfma_bf16(aq[ks], bk, sc[nt]);
      }
    }
    if (st == qt) {  // causal mask on diagonal tile
      int qg = q0 + wave * 16 + quad * 4;
      #pragma unroll
      for (int nt = 0; nt < 4; ++nt) {
        int sg = s0 + nt * 16 + l15;
        #pragma unroll
        for (int r = 0; r < 4; ++r)
          if (sg > qg + r) sc[nt][r] = -1e30f;
      }
    }
    float alpha[4];
    #pragma unroll
    for (int r = 0; r < 4; ++r) {
      float tm = fmaxf(fmaxf(sc[0][r], sc[1][r]), fmaxf(sc[2][r], sc[3][r]));
      tm = fmaxf(tm, __shfl_xor(tm, 1, 16));
      tm = fmaxf(tm, __shfl_xor(tm, 2, 16));
      tm = fmaxf(tm, __shfl_xor(tm, 4, 16));
      tm = fmaxf(tm, __shfl_xor(tm, 8, 16));
      float mnew = fmaxf(m_run[r], tm);
      alpha[r] = __expf(m_run[r] - mnew);
      m_run[r] = mnew;
      float ts = 0.f;
      #pragma unroll
      for (int nt = 0; nt < 4; ++nt) {
        float p = __expf(sc[nt][r] - mnew);
        sc[nt][r] = p;
        ts += p;
      }
      ts += __shfl_xor(ts, 1, 16);
      ts += __shfl_xor(ts, 2, 16);
      ts += __shfl_xor(ts, 4, 16);
      ts += __shfl_xor(ts, 8, 16);
      l_run[r] = l_run[r] * alpha[r] + ts;
    }
    #pragma unroll
    for (int ct = 0; ct < 16; ++ct)
      #pragma unroll
      for (int r = 0; r < 4; ++r)
        o[ct][r] *= alpha[r];
    // P: C-layout -> LDS -> A-layout (within-wave, lockstep + compiler lgkmcnt)
    #pragma unroll
    for (int nt = 0; nt < 4; ++nt)
      #pragma unroll
      for (int r = 0; r < 4; ++r)
        pw[(quad * 4 + r) * 72 + nt * 16 + l15] = __float2bfloat16(sc[nt][r]);
    #pragma unroll
    for (int ks2 = 0; ks2 < 2; ++ks2) {
      bf16x8 ap = ld16(pw + l15 * 72 + ks2 * 32 + quad * 8);
      #pragma unroll
      for (int ct = 0; ct < 16; ++ct) {
        bf16x8 bv = ld16(hsT + ((size_t)n * H2_ + ct * 16 + l15) * T_ + s0 + ks2 * 32 + quad * 8);
        o[ct] = mfma_bf16(ap, bv, o[ct]);
      }
    }
  }
  // normalize, ctx -> LDS (bf16)
  float inv[4];
  #pragma unroll
  for (int r = 0; r < 4; ++r) inv[r] = 1.f / l_run[r];
  #pragma unroll
  for (int ct = 0; ct < 16; ++ct)
    #pragma unroll
    for (int r = 0; r < 4; ++r)
      ctxlds[(wave * 16 + quad * 4 + r) * 264 + ct * 16 + l15] =
          __float2bfloat16(o[ct][r] * inv[r]);
  __syncthreads();

  // fc1: [64 rows, K=512 (ctx|hs2)] @ [128,512]^T, wave owns 32 out-channels
  f32x4 a1[4][2];
  #pragma unroll
  for (int mt = 0; mt < 4; ++mt) { a1[mt][0] = z; a1[mt][1] = z; }
  #pragma unroll
  for (int ks = 0; ks < 16; ++ks) {
    bf16x8 af[4];
    if (ks < 8) {
      #pragma unroll
      for (int mt = 0; mt < 4; ++mt)
        af[mt] = ld16(ctxlds + (mt * 16 + l15) * 264 + ks * 32 + quad * 8);
    } else {
      #pragma unroll
      for (int mt = 0; mt < 4; ++mt)
        af[mt] = ld16(hs2 + ((size_t)n * T_ + q0 + mt * 16 + l15) * H2_ + (ks - 8) * 32 + quad * 8);
    }
    #pragma unroll
    for (int nt = 0; nt < 2; ++nt) {
      bf16x8 bw = ld16(f1w + (size_t)(wave * 32 + nt * 16 + l15) * 512 + ks * 32 + quad * 8);
      #pragma unroll
      for (int mt = 0; mt < 4; ++mt)
        a1[mt][nt] = mfma_bf16(af[mt], bw, a1[mt][nt]);
    }
  }
  #pragma unroll
  for (int mt = 0; mt < 4; ++mt)
    #pragma unroll
    for (int nt = 0; nt < 2; ++nt)
      #pragma unroll
      for (int r = 0; r < 4; ++r) {
        int ch = wave * 32 + nt * 16 + l15;
        float v = a1[mt][nt][r] + fc1b[ch];
        act1[(mt * 16 + quad * 4 + r) * 136 + ch] = __float2bfloat16(fmaxf(v, 0.f));
      }
  __syncthreads();

  // fc2: K=128, wave owns 16 out-channels (51 real, padded to 64)
  f32x4 a2[4] = {z, z, z, z};
  #pragma unroll
  for (int ks = 0; ks < 4; ++ks) {
    bf16x8 bw = ld16(f2w + (wave * 16 + l15) * 128 + ks * 32 + quad * 8);
    #pragma unroll
    for (int mt = 0; mt < 4; ++mt) {
      bf16x8 af = ld16(act1 + (mt * 16 + l15) * 136 + ks * 32 + quad * 8);
      a2[mt] = mfma_bf16(af, bw, a2[mt]);
    }
  }
  #pragma unroll
  for (int mt = 0; mt < 4; ++mt)
    #pragma unroll
    for (int r = 0; r < 4; ++r) {
      int ch = wave * 16 + l15;
      int row = mt * 16 + quad * 4 + r;
      float v = a2[mt][r] + (ch < 51 ? fc2b[ch] : 0.f);
      act2[row * 68 + ch] = fmaxf(v, 0.f);
    }
  __syncthreads();

  // fc3: dot over 51, one thread per row
  if (tid < 64) {
    float s = fc3b[0];
    for (int c = 0; c < 51; ++c) s += act2[tid * 68 + c] * fc3w[c];
    dout[(size_t)n * T_ + q0 + tid] = s;
  }
}

extern "C" void kernel_launch(void* const* d_in, const int* in_sizes, int n_in,
                              void* d_out, int out_size, void* d_ws, size_t ws_size,
                              hipStream_t stream) {
  (void)in_sizes; (void)n_in; (void)out_size; (void)ws_size;
  const float* x    = (const float*)d_in[0];
  const float* Wih1 = (const float*)d_in[1];
  const float* Whh1 = (const float*)d_in[2];
  const float* bih1 = (const float*)d_in[3];
  const float* bhh1 = (const float*)d_in[4];
  const float* Wih2 = (const float*)d_in[5];
  const float* Whh2 = (const float*)d_in[6];
  const float* bih2 = (const float*)d_in[7];
  const float* bhh2 = (const float*)d_in[8];
  const float* fc1w = (const float*)d_in[9];
  const float* fc1b = (const float*)d_in[10];
  const float* fc2w = (const float*)d_in[11];
  const float* fc2b = (const float*)d_in[12];
  const float* fc3w = (const float*)d_in[13];
  const float* fc3b = (const float*)d_in[14];
  char* ws  = (char*)d_ws;
  float* out = (float*)d_out;

  hipMemsetAsync(ws, 0, ZERO_BYTES, stream);  // h/c buffers + barrier state
  setup_kernel<<<2048, 256, 0, stream>>>(x, Wih1, Whh1, bih1, bhh1,
                                         Wih2, Whh2, bih2, bhh2, fc1w, fc2w, ws);
  lstm_kernel<<<NBLK, 256, 0, stream>>>(ws, out);
  attn_fc_kernel<<<1024, 256, 0, stream>>>(ws, fc1b, fc2b, fc3w, fc3b, out);
}